// Round 8
// baseline (55.340 us; speedup 1.0000x reference)
//
#include <hip/hip_runtime.h>

// QuantumVelocityField: fused 4->128->128->6 silu MLP (fp16 MFMA, fp32 accum)
// + 3-layer RY/RZ single-qubit sim. B = 262144.
//
// R8 vs R7 (registers -- not LDS -- cap occupancy at 3 waves/SIMD):
//  - 16-row passes: one acc[8]+bf[4] pipeline live at a time -> ~100 total
//    regs -> 4-5 waves/SIMD under __launch_bounds__(256,4) (cap 128).
//  - NO LDS weight staging: A-frags/biases read straight from the packed
//    d_ws image (36KB, L1/L2-resident, lane-linear coalesced). No
//    __syncthreads, LDS = 1.5KB param strip -> LDS never caps occupancy.
//  - grid 2048 x 4 waves x 32 rows; pack kernel unchanged from R7.

typedef _Float16 half8 __attribute__((ext_vector_type(8)));
typedef _Float16 half4 __attribute__((ext_vector_type(4)));
typedef _Float16 half2 __attribute__((ext_vector_type(2)));
typedef float f32x4 __attribute__((ext_vector_type(4)));
typedef float f32x2 __attribute__((ext_vector_type(2)));

#define NBLOCKS 2048          // 2048 blocks * 4 waves * 32 rows = 262144
#define WS_IMG_BYTES 36864

union Half8U { half8 v; half2 h2[4]; };

__device__ __forceinline__ half2 silu2(float x0, float x1) {
    float s0 = __fdividef(x0, 1.0f + __expf(-x0));
    float s1 = __fdividef(x1, 1.0f + __expf(-x1));
    return __builtin_bit_cast(half2, __builtin_amdgcn_cvt_pkrtz(s0, s1));
}
__device__ __forceinline__ unsigned int pk16(float x0, float x1) {
    return __builtin_bit_cast(unsigned int, __builtin_amdgcn_cvt_pkrtz(x0, x1));
}

#define DSFENCE() do { asm volatile("s_waitcnt lgkmcnt(0)" ::: "memory"); \
                       __builtin_amdgcn_wave_barrier(); } while (0)

// ---------------------------------------------------------------------------
// Image layout (identical to R7):
//   h[0,16384)      W2 frags: f=s*8+nt: h[f*512 + l*8 + j] =
//                   W2[s*32+(j>>2)*16+(l>>4)*4+(j&3)][nt*16+(l&15)]
//   h[16384,16896)  W1 compact: h[16384 + nt*64 + ln*4 + j] = W1[j][nt*16+ln]
//   h[16896,17664)  W3 compact: h[16896 + ((s*6+ln)*4+q)*8 + j] =
//                   W3[(s*32+(j>>2)*16+q*4+(j&3))*6 + ln]
//   f[8832,8960)    b1;  f[8960,9088) b2;  pad to 36864B
// ---------------------------------------------------------------------------
__global__ void qvf_pack(const float* __restrict__ W1g, const float* __restrict__ b1g,
                         const float* __restrict__ W2g, const float* __restrict__ b2g,
                         const float* __restrict__ W3g, const float* __restrict__ b3g,
                         unsigned char* __restrict__ ws) {
    _Float16* h = (_Float16*)ws;
    float*    f = (float*)ws;
    const int b = blockIdx.x, tid = threadIdx.x;
    if (b < 64) {
        int i = b * 256 + tid;                  // coalesced W2 read
        int k = i >> 7, n2 = i & 127;
        float wv = W2g[i];
        int s = k >> 5, hi = (k >> 4) & 1, qv = (k >> 2) & 3, c = k & 3;
        int frag = s * 8 + (n2 >> 4), l = qv * 16 + (n2 & 15), j = hi * 4 + c;
        h[frag * 512 + l * 8 + j] = (_Float16)wv;
    } else {
        for (int i = tid; i < 512; i += 256) {          // W1 compact
            int j = i & 3, ln = (i >> 2) & 15, nt = i >> 6;
            h[16384 + i] = (_Float16)W1g[j * 128 + nt * 16 + ln];
        }
        for (int i = tid; i < 768; i += 256) {          // W3 compact
            int j = i & 7, t2 = i >> 3;
            int q = t2 & 3, u = t2 >> 2;
            int ln = u % 6, s = u / 6;
            int k = s * 32 + ((j >> 2) << 4) + q * 4 + (j & 3);
            h[16896 + i] = (_Float16)W3g[k * 6 + ln];
        }
        if (tid < 128) { f[8832 + tid] = b1g[tid]; f[8960 + tid] = b2g[tid]; }
        for (int i = 9088 + tid; i < 9216; i += 256) f[i] = 0.f;
    }
}

// ---------------------------------------------------------------------------
template <bool PREPACK>
__global__ __launch_bounds__(256, 4)
void qvf_kernel(const float* __restrict__ tg, const float* __restrict__ blg,
                const float* __restrict__ W1g, const float* __restrict__ b1g,
                const float* __restrict__ W2g, const float* __restrict__ b2g,
                const float* __restrict__ W3g, const float* __restrict__ b3g,
                const unsigned char* __restrict__ ws,
                float* __restrict__ out) {
    extern __shared__ __align__(16) unsigned char sDyn[];

    const int tid  = threadIdx.x;
    const int w    = tid >> 6;
    const int lane = tid & 63;
    const int q    = lane >> 4;
    const int ln   = lane & 15;

    const _Float16 *pW2, *pW1, *pW3;
    const float    *pB1, *pB2;
    unsigned int   *sPU;

    if constexpr (PREPACK) {
        pW2 = (const _Float16*)ws;
        pW1 = (const _Float16*)(ws + 32768);
        pW3 = (const _Float16*)(ws + 33792);
        pB1 = (const float*)(ws + 35328);
        pB2 = (const float*)(ws + 35840);
        sPU = (unsigned int*)sDyn + w * 96;
    } else {
        // stage the same image into dynamic LDS (fallback path)
        _Float16* h = (_Float16*)sDyn;
        float*    f = (float*)sDyn;
        for (int i = tid; i < 16384; i += 256) {
            int k = i >> 7, n2 = i & 127;
            float wv = W2g[i];
            int s = k >> 5, hi = (k >> 4) & 1, qv = (k >> 2) & 3, c = k & 3;
            int frag = s * 8 + (n2 >> 4), l = qv * 16 + (n2 & 15), j = hi * 4 + c;
            h[frag * 512 + l * 8 + j] = (_Float16)wv;
        }
        for (int i = tid; i < 512; i += 256) {
            int j = i & 3, l2 = (i >> 2) & 15, nt = i >> 6;
            h[16384 + i] = (_Float16)W1g[j * 128 + nt * 16 + l2];
        }
        for (int i = tid; i < 768; i += 256) {
            int j = i & 7, t2 = i >> 3;
            int q2 = t2 & 3, u = t2 >> 2;
            int l2 = u % 6, s = u / 6;
            int k = s * 32 + ((j >> 2) << 4) + q2 * 4 + (j & 3);
            h[16896 + i] = (_Float16)W3g[k * 6 + l2];
        }
        if (tid < 128) { f[8832 + tid] = b1g[tid]; f[8960 + tid] = b2g[tid]; }
        pW2 = (const _Float16*)sDyn;
        pW1 = (const _Float16*)(sDyn + 32768);
        pW3 = (const _Float16*)(sDyn + 33792);
        pB1 = (const float*)(sDyn + 35328);
        pB2 = (const float*)(sDyn + 35840);
        sPU = (unsigned int*)(sDyn + 36864) + w * 96;
        __syncthreads();
    }
    float* sPF = (float*)sPU;

    // b3 per-lane regs
    float b3c[4];
    #pragma unroll
    for (int r = 0; r < 4; ++r) {
        int n3 = 4 * q + r;
        b3c[r] = (n3 < 6) ? b3g[n3] : 0.0f;
    }

    const int rowb = blockIdx.x * 128 + w * 32;   // this wave's 32 rows

    // ---- two 16-row passes; only one acc[8]+bf[4] pipeline live at a time ----
    #pragma unroll
    for (int p = 0; p < 2; ++p) {
        // input frag (q==0 lanes): [t, bloch] in k-slots 0..3
        half8 bIn = {};
        if (q == 0) {
            int m = rowb + p * 16 + ln;
            bIn[0] = (_Float16)tg[m];
            bIn[1] = (_Float16)blg[3 * m + 0];
            bIn[2] = (_Float16)blg[3 * m + 1];
            bIn[3] = (_Float16)blg[3 * m + 2];
        }

        // layer 1: C-init = b1 frag
        f32x4 acc1[8];
        #pragma unroll
        for (int nt = 0; nt < 8; ++nt) {
            half8 a1 = {};
            if (q == 0) {
                half4 lo = *(const half4*)&pW1[nt * 64 + ln * 4];
                a1[0] = lo[0]; a1[1] = lo[1]; a1[2] = lo[2]; a1[3] = lo[3];
            }
            f32x4 bb = *(const f32x4*)&pB1[nt * 16 + 4 * q];
            acc1[nt] = __builtin_amdgcn_mfma_f32_16x16x32_f16(a1, bIn, bb, 0, 0, 0);
        }

        // epilogue 1: silu -> layer-2 B frags
        half8 bf2[4];
        #pragma unroll
        for (int s = 0; s < 4; ++s) {
            Half8U u;
            #pragma unroll
            for (int hj = 0; hj < 2; ++hj) {
                int nt = 2 * s + hj;
                u.h2[hj * 2 + 0] = silu2(acc1[nt][0], acc1[nt][1]);
                u.h2[hj * 2 + 1] = silu2(acc1[nt][2], acc1[nt][3]);
            }
            bf2[s] = u.v;
        }

        // layer 2: fragment-major A, C-init = b2 at s==0
        f32x4 acc2[8];
        #pragma unroll
        for (int s = 0; s < 4; ++s) {
            #pragma unroll
            for (int nt = 0; nt < 8; ++nt) {
                half8 a2 = *(const half8*)&pW2[(s * 8 + nt) * 512 + lane * 8];
                if (s == 0) {
                    f32x4 bb = *(const f32x4*)&pB2[nt * 16 + 4 * q];
                    acc2[nt] = __builtin_amdgcn_mfma_f32_16x16x32_f16(a2, bf2[0], bb, 0, 0, 0);
                } else {
                    acc2[nt] = __builtin_amdgcn_mfma_f32_16x16x32_f16(a2, bf2[s], acc2[nt], 0, 0, 0);
                }
            }
        }

        // epilogue 2: silu -> layer-3 B frags
        half8 bf3[4];
        #pragma unroll
        for (int s = 0; s < 4; ++s) {
            Half8U u;
            #pragma unroll
            for (int hj = 0; hj < 2; ++hj) {
                int nt = 2 * s + hj;
                u.h2[hj * 2 + 0] = silu2(acc2[nt][0], acc2[nt][1]);
                u.h2[hj * 2 + 1] = silu2(acc2[nt][2], acc2[nt][3]);
            }
            bf3[s] = u.v;
        }

        // layer 3: C-init = b3 regs
        f32x4 acc3 = (f32x4){b3c[0], b3c[1], b3c[2], b3c[3]};
        #pragma unroll
        for (int s = 0; s < 4; ++s) {
            half8 a3 = {};
            if (ln < 6) a3 = *(const half8*)&pW3[((s * 6 + ln) * 4 + q) * 8];
            acc3 = __builtin_amdgcn_mfma_f32_16x16x32_f16(a3, bf3[s], acc3, 0, 0, 0);
        }

        // epilogue 3: pack params fp16 -> wave strip (stride-3 dwords)
        int row = p * 16 + ln;
        if (q == 0) {
            sPU[row * 3 + 0] = pk16(acc3[0], acc3[1]);  // th1, ph1
            sPU[row * 3 + 1] = pk16(acc3[2], acc3[3]);  // th2, ph2
        } else if (q == 1) {
            sPU[row * 3 + 2] = pk16(acc3[0], acc3[1]);  // th3, ph3
        }
    }
    DSFENCE();   // wave-private: params visible to all lanes

    // ---- circuit sim: lanes 0..31, one row each ----
    if (lane < 32) {
        half2 h0 = __builtin_bit_cast(half2, sPU[lane * 3 + 0]);
        half2 h1 = __builtin_bit_cast(half2, sPU[lane * 3 + 1]);
        half2 h2 = __builtin_bit_cast(half2, sPU[lane * 3 + 2]);
        float pr[6] = {(float)h0[0], (float)h0[1], (float)h1[0],
                       (float)h1[1], (float)h2[0], (float)h2[1]};
        float ar = 1.f, ai = 0.f, br = 0.f, bi = 0.f;
        #pragma unroll
        for (int l = 0; l < 3; ++l) {
            float th = pr[2 * l] * 0.5f;
            float ph = pr[2 * l + 1] * 0.5f;
            float s1, c1, se, ce;
            __sincosf(th, &s1, &c1);
            float a1r = c1 * ar - s1 * br, a1i = c1 * ai - s1 * bi;
            float b1r = s1 * ar + c1 * br, b1i = s1 * ai + c1 * bi;
            __sincosf(ph, &se, &ce);
            ar = ce * a1r + se * a1i; ai = ce * a1i - se * a1r;
            br = ce * b1r - se * b1i; bi = ce * b1i + se * b1r;
        }
        // same-lane same-address: ordered within a lane
        sPF[lane * 3 + 0] = 2.f * (ar * br + ai * bi);
        sPF[lane * 3 + 1] = 2.f * (ar * bi - ai * br);
        sPF[lane * 3 + 2] = ar * ar + ai * ai - br * br - bi * bi;
    }
    DSFENCE();   // outputs visible cross-lane

    // ---- coalesced stores: 96 floats per wave, 48-lane dwordx2 ----
    if (lane < 48) {
        f32x2 vv = *(const f32x2*)&sPF[2 * lane];
        *(f32x2*)&out[3 * rowb + 2 * lane] = vv;
    }
}

extern "C" void kernel_launch(void* const* d_in, const int* in_sizes, int n_in,
                              void* d_out, int out_size, void* d_ws, size_t ws_size,
                              hipStream_t stream) {
    const float* t  = (const float*)d_in[0];
    const float* bl = (const float*)d_in[1];
    const float* W1 = (const float*)d_in[2];
    const float* b1 = (const float*)d_in[3];
    const float* W2 = (const float*)d_in[4];
    const float* b2 = (const float*)d_in[5];
    const float* W3 = (const float*)d_in[6];
    const float* b3 = (const float*)d_in[7];
    float* out = (float*)d_out;

    if (ws_size >= WS_IMG_BYTES) {
        unsigned char* ws = (unsigned char*)d_ws;
        qvf_pack<<<65, 256, 0, stream>>>(W1, b1, W2, b2, W3, b3, ws);
        qvf_kernel<true><<<NBLOCKS, 256, 1536, stream>>>(t, bl, W1, b1, W2, b2, W3, b3, ws, out);
    } else {
        qvf_kernel<false><<<NBLOCKS, 256, 36864 + 1536, stream>>>(t, bl, W1, b1, W2, b2, W3, b3, nullptr, out);
    }
}

// Round 10
// 48.304 us; speedup vs baseline: 1.1457x; 1.1457x over previous
//
#include <hip/hip_runtime.h>

// QuantumVelocityField: fused 4->128->128->6 silu MLP (fp16 MFMA, fp32 accum)
// + 3-layer RY/RZ single-qubit sim. B = 262144.
//
// R10 = R9 with the param-strip address fixed (w*1024, not w*2048: W3's pad
// holes are 640B per 1024B s-block; w*2048 ran waves 2-3 out of bounds and
// wave 1 over live W3 weights -> absmax 1.0).
//
// R9 design: R7's LDS-resident weights + R8's small live set:
//  - 16-row passes: one acc[8]+bf[4] pipeline live -> __launch_bounds__(256,4)
//    spill-free (R8-proven).
//  - W1 padded [nt][ln][8] & W3 padded [s][ln16][q][8]: UNGATED b128 A-reads.
//  - circuit *0.5 folded into W3/b3 at pack time.
//  - param strips in W3-pad holes: LDS = 39936B -> 4 blocks/CU.

typedef _Float16 half8 __attribute__((ext_vector_type(8)));
typedef _Float16 half2 __attribute__((ext_vector_type(2)));
typedef float f32x4 __attribute__((ext_vector_type(4)));
typedef float f32x2 __attribute__((ext_vector_type(2)));

#define NBLOCKS 2048          // 2048 blocks * 4 waves * 32 rows = 262144
#define WS_IMG_BYTES 39936

union Half8U { half8 v; half2 h2[4]; };

__device__ __forceinline__ half2 silu2(float x0, float x1) {
    float s0 = __fdividef(x0, 1.0f + __expf(-x0));
    float s1 = __fdividef(x1, 1.0f + __expf(-x1));
    return __builtin_bit_cast(half2, __builtin_amdgcn_cvt_pkrtz(s0, s1));
}
__device__ __forceinline__ unsigned int pk16(float x0, float x1) {
    return __builtin_bit_cast(unsigned int, __builtin_amdgcn_cvt_pkrtz(x0, x1));
}

#define DSFENCE() do { asm volatile("s_waitcnt lgkmcnt(0)" ::: "memory"); \
                       __builtin_amdgcn_wave_barrier(); } while (0)

// ---------------------------------------------------------------------------
// Image layout (39936 B):
//   h[0,16384)       W2 frags: f=s*8+nt: h[f*512 + l*8 + j] =
//                    W2[s*32+(j>>2)*16+(l>>4)*4+(j&3)][nt*16+(l&15)]
//   h[16384,17408)   W1 padded: h[16384 + nt*128 + ln*8 + j] =
//                    (j<4) ? W1[j][nt*16+ln] : 0
//   h[17408,19456)   W3 padded (x0.5): h[17408 + s*512 + ln*32 + q*8 + j] =
//                    (ln<6) ? 0.5*W3[(s*32+(j>>2)*16+q*4+(j&3))*6+ln] : 0
//                    (runtime: wave w's 384B param strip lives in s-block w's
//                     ln>=6 hole: bytes 34816 + w*1024 + [384,768) of sRaw)
//   f[9728,9856)     b1;  f[9856,9984) b2.   Total 39936 B.
// ---------------------------------------------------------------------------
__global__ void qvf_pack(const float* __restrict__ W1g, const float* __restrict__ b1g,
                         const float* __restrict__ W2g, const float* __restrict__ b2g,
                         const float* __restrict__ W3g, const float* __restrict__ b3g,
                         unsigned char* __restrict__ ws) {
    _Float16* h = (_Float16*)ws;
    float*    f = (float*)ws;
    const int b = blockIdx.x, tid = threadIdx.x;
    if (b < 64) {
        int i = b * 256 + tid;                  // coalesced W2 read
        int k = i >> 7, n2 = i & 127;
        float wv = W2g[i];
        int s = k >> 5, hi = (k >> 4) & 1, qv = (k >> 2) & 3, c = k & 3;
        int frag = s * 8 + (n2 >> 4), l = qv * 16 + (n2 & 15), j = hi * 4 + c;
        h[frag * 512 + l * 8 + j] = (_Float16)wv;
    } else {
        for (int i = tid; i < 1024; i += 256) {         // W1 padded
            int j = i & 7, ln = (i >> 3) & 15, nt = i >> 7;
            h[16384 + i] = (j < 4) ? (_Float16)W1g[j * 128 + nt * 16 + ln]
                                   : (_Float16)0.f;
        }
        for (int i = tid; i < 2048; i += 256) {         // W3 padded, x0.5
            int j = i & 7, q = (i >> 3) & 3, ln = (i >> 5) & 15, s = i >> 9;
            int k = s * 32 + ((j >> 2) << 4) + q * 4 + (j & 3);
            h[17408 + i] = (ln < 6) ? (_Float16)(0.5f * W3g[k * 6 + ln])
                                    : (_Float16)0.f;
        }
        if (tid < 128) { f[9728 + tid] = b1g[tid]; f[9856 + tid] = b2g[tid]; }
    }
}

// ---------------------------------------------------------------------------
template <bool PREPACK>
__global__ __launch_bounds__(256, 4)
void qvf_kernel(const float* __restrict__ tg, const float* __restrict__ blg,
                const float* __restrict__ W1g, const float* __restrict__ b1g,
                const float* __restrict__ W2g, const float* __restrict__ b2g,
                const float* __restrict__ W3g, const float* __restrict__ b3g,
                const unsigned char* __restrict__ ws,
                float* __restrict__ out) {
    __shared__ __align__(16) unsigned char sRaw[39936];
    const _Float16* sW2 = (const _Float16*)sRaw;               // 32 frags x 1KB
    const _Float16* sW1 = (const _Float16*)(sRaw + 32768);     // padded
    const _Float16* sW3 = (const _Float16*)(sRaw + 34816);     // padded (x0.5)
    const float*    sB1 = (const float*)(sRaw + 38912);
    const float*    sB2 = (const float*)(sRaw + 39424);

    const int tid  = threadIdx.x;
    const int w    = tid >> 6;
    const int lane = tid & 63;
    const int q    = lane >> 4;
    const int ln   = lane & 15;

    // wave w's 384B param strip: s-block w's ln>=6 hole (finite garbage if
    // read by the ungated a3 loads -- feeds only never-stored D rows)
    unsigned int* sPU = (unsigned int*)(sRaw + 34816 + w * 1024 + 384);
    float*        sPF = (float*)sPU;

    // ---- stage the weight image ----
    if (PREPACK) {
        for (int i = tid; i < 2496; i += 256) {     // 2496 * 16B = 39936B
            *(f32x4*)(sRaw + i * 16) = *(const f32x4*)(ws + i * 16);
        }
    } else {
        _Float16* h = (_Float16*)sRaw;
        float*    f = (float*)sRaw;
        for (int i = tid; i < 16384; i += 256) {
            int k = i >> 7, n2 = i & 127;
            float wv = W2g[i];
            int s = k >> 5, hi = (k >> 4) & 1, qv = (k >> 2) & 3, c = k & 3;
            int frag = s * 8 + (n2 >> 4), l = qv * 16 + (n2 & 15), j = hi * 4 + c;
            h[frag * 512 + l * 8 + j] = (_Float16)wv;
        }
        for (int i = tid; i < 1024; i += 256) {
            int j = i & 7, l2 = (i >> 3) & 15, nt = i >> 7;
            h[16384 + i] = (j < 4) ? (_Float16)W1g[j * 128 + nt * 16 + l2]
                                   : (_Float16)0.f;
        }
        for (int i = tid; i < 2048; i += 256) {
            int j = i & 7, q2 = (i >> 3) & 3, l2 = (i >> 5) & 15, s = i >> 9;
            int k = s * 32 + ((j >> 2) << 4) + q2 * 4 + (j & 3);
            h[17408 + i] = (l2 < 6) ? (_Float16)(0.5f * W3g[k * 6 + l2])
                                    : (_Float16)0.f;
        }
        if (tid < 128) { f[9728 + tid] = b1g[tid]; f[9856 + tid] = b2g[tid]; }
    }

    // b3 per-lane regs, pre-scaled by 0.5 (circuit uses th/2, ph/2 directly)
    float b3c[4];
    #pragma unroll
    for (int r = 0; r < 4; ++r) {
        int n3 = 4 * q + r;
        b3c[r] = (n3 < 6) ? 0.5f * b3g[n3] : 0.0f;
    }

    const int rowb = blockIdx.x * 128 + w * 32;   // this wave's 32 rows

    // ---- prefetch both passes' inputs (q==0 lanes) ----
    half8 bIn[2] = {{}, {}};
    if (q == 0) {
        #pragma unroll
        for (int p = 0; p < 2; ++p) {
            int m = rowb + p * 16 + ln;
            bIn[p][0] = (_Float16)tg[m];
            bIn[p][1] = (_Float16)blg[3 * m + 0];
            bIn[p][2] = (_Float16)blg[3 * m + 1];
            bIn[p][3] = (_Float16)blg[3 * m + 2];
        }
    }

    __syncthreads();

    // ---- two 16-row passes; one acc[8]+bf[4] pipeline live at a time ----
    #pragma unroll
    for (int p = 0; p < 2; ++p) {
        // layer 1: ungated padded A-frags; C-init = b1 frag
        f32x4 acc1[8];
        #pragma unroll
        for (int nt = 0; nt < 8; ++nt) {
            half8 a1 = *(const half8*)&sW1[nt * 128 + ln * 8];
            f32x4 bb = *(const f32x4*)&sB1[nt * 16 + 4 * q];
            acc1[nt] = __builtin_amdgcn_mfma_f32_16x16x32_f16(a1, bIn[p], bb, 0, 0, 0);
        }

        // epilogue 1: silu -> layer-2 B frags
        half8 bf2[4];
        #pragma unroll
        for (int s = 0; s < 4; ++s) {
            Half8U u;
            #pragma unroll
            for (int hj = 0; hj < 2; ++hj) {
                int nt = 2 * s + hj;
                u.h2[hj * 2 + 0] = silu2(acc1[nt][0], acc1[nt][1]);
                u.h2[hj * 2 + 1] = silu2(acc1[nt][2], acc1[nt][3]);
            }
            bf2[s] = u.v;
        }

        // layer 2: fragment-major A (lane-linear b128); C-init = b2 at s==0
        f32x4 acc2[8];
        #pragma unroll
        for (int s = 0; s < 4; ++s) {
            #pragma unroll
            for (int nt = 0; nt < 8; ++nt) {
                half8 a2 = *(const half8*)&sW2[(s * 8 + nt) * 512 + lane * 8];
                if (s == 0) {
                    f32x4 bb = *(const f32x4*)&sB2[nt * 16 + 4 * q];
                    acc2[nt] = __builtin_amdgcn_mfma_f32_16x16x32_f16(a2, bf2[0], bb, 0, 0, 0);
                } else {
                    acc2[nt] = __builtin_amdgcn_mfma_f32_16x16x32_f16(a2, bf2[s], acc2[nt], 0, 0, 0);
                }
            }
        }

        // epilogue 2: silu -> layer-3 B frags
        half8 bf3[4];
        #pragma unroll
        for (int s = 0; s < 4; ++s) {
            Half8U u;
            #pragma unroll
            for (int hj = 0; hj < 2; ++hj) {
                int nt = 2 * s + hj;
                u.h2[hj * 2 + 0] = silu2(acc2[nt][0], acc2[nt][1]);
                u.h2[hj * 2 + 1] = silu2(acc2[nt][2], acc2[nt][3]);
            }
            bf3[s] = u.v;
        }

        // layer 3: ungated padded A-frags; C-init = b3/2 regs
        f32x4 acc3 = (f32x4){b3c[0], b3c[1], b3c[2], b3c[3]};
        #pragma unroll
        for (int s = 0; s < 4; ++s) {
            half8 a3 = *(const half8*)&sW3[s * 512 + ln * 32 + q * 8];
            acc3 = __builtin_amdgcn_mfma_f32_16x16x32_f16(a3, bf3[s], acc3, 0, 0, 0);
        }

        // epilogue 3: pack half-angle params fp16 -> wave strip
        int row = p * 16 + ln;
        if (q == 0) {
            sPU[row * 3 + 0] = pk16(acc3[0], acc3[1]);  // th1/2, ph1/2
            sPU[row * 3 + 1] = pk16(acc3[2], acc3[3]);  // th2/2, ph2/2
        } else if (q == 1) {
            sPU[row * 3 + 2] = pk16(acc3[0], acc3[1]);  // th3/2, ph3/2
        }
    }
    DSFENCE();   // wave-private: params visible to all lanes

    // ---- circuit sim: lanes 0..31, one row each (params already half-angle) ----
    if (lane < 32) {
        half2 h0 = __builtin_bit_cast(half2, sPU[lane * 3 + 0]);
        half2 h1 = __builtin_bit_cast(half2, sPU[lane * 3 + 1]);
        half2 h2 = __builtin_bit_cast(half2, sPU[lane * 3 + 2]);
        float pr[6] = {(float)h0[0], (float)h0[1], (float)h1[0],
                       (float)h1[1], (float)h2[0], (float)h2[1]};
        float ar = 1.f, ai = 0.f, br = 0.f, bi = 0.f;
        #pragma unroll
        for (int l = 0; l < 3; ++l) {
            float th = pr[2 * l];
            float ph = pr[2 * l + 1];
            float s1, c1, se, ce;
            __sincosf(th, &s1, &c1);
            float a1r = c1 * ar - s1 * br, a1i = c1 * ai - s1 * bi;
            float b1r = s1 * ar + c1 * br, b1i = s1 * ai + c1 * bi;
            __sincosf(ph, &se, &ce);
            ar = ce * a1r + se * a1i; ai = ce * a1i - se * a1r;
            br = ce * b1r - se * b1i; bi = ce * b1i + se * b1r;
        }
        // same-lane same-address: ordered within a lane
        sPF[lane * 3 + 0] = 2.f * (ar * br + ai * bi);
        sPF[lane * 3 + 1] = 2.f * (ar * bi - ai * br);
        sPF[lane * 3 + 2] = ar * ar + ai * ai - br * br - bi * bi;
    }
    DSFENCE();   // results visible cross-lane

    // ---- coalesced stores: 96 floats per wave, 48-lane dwordx2 ----
    if (lane < 48) {
        f32x2 vv = *(const f32x2*)&sPF[2 * lane];
        *(f32x2*)&out[3 * rowb + 2 * lane] = vv;
    }
}

extern "C" void kernel_launch(void* const* d_in, const int* in_sizes, int n_in,
                              void* d_out, int out_size, void* d_ws, size_t ws_size,
                              hipStream_t stream) {
    const float* t  = (const float*)d_in[0];
    const float* bl = (const float*)d_in[1];
    const float* W1 = (const float*)d_in[2];
    const float* b1 = (const float*)d_in[3];
    const float* W2 = (const float*)d_in[4];
    const float* b2 = (const float*)d_in[5];
    const float* W3 = (const float*)d_in[6];
    const float* b3 = (const float*)d_in[7];
    float* out = (float*)d_out;

    if (ws_size >= WS_IMG_BYTES) {
        unsigned char* ws = (unsigned char*)d_ws;
        qvf_pack<<<65, 256, 0, stream>>>(W1, b1, W2, b2, W3, b3, ws);
        qvf_kernel<true><<<NBLOCKS, 256, 0, stream>>>(t, bl, W1, b1, W2, b2, W3, b3, ws, out);
    } else {
        qvf_kernel<false><<<NBLOCKS, 256, 0, stream>>>(t, bl, W1, b1, W2, b2, W3, b3, nullptr, out);
    }
}

// Round 11
// 35.557 us; speedup vs baseline: 1.5564x; 1.3585x over previous
//
#include <hip/hip_runtime.h>

// QuantumVelocityField: fused 4->128->128->6 silu MLP (fp16 MFMA, fp32 accum)
// + 3-layer RY/RZ single-qubit sim. B = 262144.
//
// R11 vs R10 (issue-bound; occupancy 23->33% changed nothing; R10's loss vs
// R7 was per-block staging + per-wave prologue amortization):
//  - grid 1024, 64 rows/wave: 4 x 16-row passes in 2 groups (circuit + store
//    after each group; strip reused). Staging/prologue cost halved.
//  - exp2-domain fold: W1,b1,b2 scaled by log2e at pack time (W2 unchanged --
//    the folds cancel; W3 gets 0.5/log2e). exp(-x) = v_exp_f32(-x') raw:
//    one v_mul per silu deleted, shorter dep chain.
//  - __launch_bounds__(256,3): occupancy lever is dead in 23-33% range;
//    choose spill-safety.

typedef _Float16 half8 __attribute__((ext_vector_type(8)));
typedef _Float16 half2 __attribute__((ext_vector_type(2)));
typedef float f32x4 __attribute__((ext_vector_type(4)));
typedef float f32x2 __attribute__((ext_vector_type(2)));

#define NBLOCKS 1024          // 1024 blocks * 4 waves * 64 rows = 262144
#define WS_IMG_BYTES 39936
#define C2E 1.4426950408889634f   // log2(e)

union Half8U { half8 v; half2 h2[4]; };

// x' = log2e * x (pre-scaled upstream). Returns fp16( x'*sigmoid(x) * 1 ) in
// the scaled domain: h' = x' * rcp(1 + 2^(-x')) = log2e * silu(x).
__device__ __forceinline__ half2 silu2x(float x0, float x1) {
    float e0 = __builtin_amdgcn_exp2f(-x0);
    float e1 = __builtin_amdgcn_exp2f(-x1);
    float s0 = x0 * __builtin_amdgcn_rcpf(1.0f + e0);
    float s1 = x1 * __builtin_amdgcn_rcpf(1.0f + e1);
    return __builtin_bit_cast(half2, __builtin_amdgcn_cvt_pkrtz(s0, s1));
}
__device__ __forceinline__ unsigned int pk16(float x0, float x1) {
    return __builtin_bit_cast(unsigned int, __builtin_amdgcn_cvt_pkrtz(x0, x1));
}

#define DSFENCE() do { asm volatile("s_waitcnt lgkmcnt(0)" ::: "memory"); \
                       __builtin_amdgcn_wave_barrier(); } while (0)

// ---------------------------------------------------------------------------
// Image layout (39936 B):
//   h[0,16384)       W2 frags (UNSCALED): f=s*8+nt: h[f*512 + l*8 + j] =
//                    W2[s*32+(j>>2)*16+(l>>4)*4+(j&3)][nt*16+(l&15)]
//   h[16384,17408)   W1 padded, x log2e: h[16384 + nt*128 + ln*8 + j] =
//                    (j<4) ? log2e*W1[j][nt*16+ln] : 0
//   h[17408,19456)   W3 padded, x 0.5/log2e: h[17408 + s*512 + ln*32 + q*8+j]
//                    = (ln<6) ? (0.5/log2e)*W3[(s*32+(j>>2)*16+q*4+(j&3))*6+ln] : 0
//                    (runtime: wave w's 384B param strip in s-block w's ln>=6
//                     hole: bytes 34816 + w*1024 + [384,768))
//   f[9728,9856)     b1 x log2e;  f[9856,9984) b2 x log2e.  Total 39936 B.
// ---------------------------------------------------------------------------
__global__ void qvf_pack(const float* __restrict__ W1g, const float* __restrict__ b1g,
                         const float* __restrict__ W2g, const float* __restrict__ b2g,
                         const float* __restrict__ W3g, const float* __restrict__ b3g,
                         unsigned char* __restrict__ ws) {
    _Float16* h = (_Float16*)ws;
    float*    f = (float*)ws;
    const int b = blockIdx.x, tid = threadIdx.x;
    if (b < 64) {
        int i = b * 256 + tid;                  // coalesced W2 read
        int k = i >> 7, n2 = i & 127;
        float wv = W2g[i];
        int s = k >> 5, hi = (k >> 4) & 1, qv = (k >> 2) & 3, c = k & 3;
        int frag = s * 8 + (n2 >> 4), l = qv * 16 + (n2 & 15), j = hi * 4 + c;
        h[frag * 512 + l * 8 + j] = (_Float16)wv;
    } else {
        for (int i = tid; i < 1024; i += 256) {         // W1 padded, x log2e
            int j = i & 7, ln = (i >> 3) & 15, nt = i >> 7;
            h[16384 + i] = (j < 4) ? (_Float16)(C2E * W1g[j * 128 + nt * 16 + ln])
                                   : (_Float16)0.f;
        }
        for (int i = tid; i < 2048; i += 256) {         // W3 padded, x 0.5/log2e
            int j = i & 7, q = (i >> 3) & 3, ln = (i >> 5) & 15, s = i >> 9;
            int k = s * 32 + ((j >> 2) << 4) + q * 4 + (j & 3);
            h[17408 + i] = (ln < 6) ? (_Float16)((0.5f / C2E) * W3g[k * 6 + ln])
                                    : (_Float16)0.f;
        }
        if (tid < 128) { f[9728 + tid] = C2E * b1g[tid]; f[9856 + tid] = C2E * b2g[tid]; }
    }
}

// ---------------------------------------------------------------------------
template <bool PREPACK>
__global__ __launch_bounds__(256, 3)
void qvf_kernel(const float* __restrict__ tg, const float* __restrict__ blg,
                const float* __restrict__ W1g, const float* __restrict__ b1g,
                const float* __restrict__ W2g, const float* __restrict__ b2g,
                const float* __restrict__ W3g, const float* __restrict__ b3g,
                const unsigned char* __restrict__ ws,
                float* __restrict__ out) {
    __shared__ __align__(16) unsigned char sRaw[39936];
    const _Float16* sW2 = (const _Float16*)sRaw;               // 32 frags x 1KB
    const _Float16* sW1 = (const _Float16*)(sRaw + 32768);     // padded, x c
    const _Float16* sW3 = (const _Float16*)(sRaw + 34816);     // padded, x 0.5/c
    const float*    sB1 = (const float*)(sRaw + 38912);
    const float*    sB2 = (const float*)(sRaw + 39424);

    const int tid  = threadIdx.x;
    const int w    = tid >> 6;
    const int lane = tid & 63;
    const int q    = lane >> 4;
    const int ln   = lane & 15;

    // wave w's 384B param strip: s-block w's ln>=6 hole (ungated a3 reads of
    // it feed only never-stored D rows)
    unsigned int* sPU = (unsigned int*)(sRaw + 34816 + w * 1024 + 384);
    float*        sPF = (float*)sPU;

    // ---- stage the weight image ----
    if (PREPACK) {
        for (int i = tid; i < 2496; i += 256) {     // 2496 * 16B = 39936B
            *(f32x4*)(sRaw + i * 16) = *(const f32x4*)(ws + i * 16);
        }
    } else {
        _Float16* h = (_Float16*)sRaw;
        float*    f = (float*)sRaw;
        for (int i = tid; i < 16384; i += 256) {
            int k = i >> 7, n2 = i & 127;
            float wv = W2g[i];
            int s = k >> 5, hi = (k >> 4) & 1, qv = (k >> 2) & 3, c = k & 3;
            int frag = s * 8 + (n2 >> 4), l = qv * 16 + (n2 & 15), j = hi * 4 + c;
            h[frag * 512 + l * 8 + j] = (_Float16)wv;
        }
        for (int i = tid; i < 1024; i += 256) {
            int j = i & 7, l2 = (i >> 3) & 15, nt = i >> 7;
            h[16384 + i] = (j < 4) ? (_Float16)(C2E * W1g[j * 128 + nt * 16 + l2])
                                   : (_Float16)0.f;
        }
        for (int i = tid; i < 2048; i += 256) {
            int j = i & 7, q2 = (i >> 3) & 3, l2 = (i >> 5) & 15, s = i >> 9;
            int k = s * 32 + ((j >> 2) << 4) + q2 * 4 + (j & 3);
            h[17408 + i] = (l2 < 6) ? (_Float16)((0.5f / C2E) * W3g[k * 6 + l2])
                                    : (_Float16)0.f;
        }
        if (tid < 128) { f[9728 + tid] = C2E * b1g[tid]; f[9856 + tid] = C2E * b2g[tid]; }
    }

    // b3 per-lane regs, x0.5 (half-angle; note: NOT exp2-scaled)
    float b3c[4];
    #pragma unroll
    for (int r = 0; r < 4; ++r) {
        int n3 = 4 * q + r;
        b3c[r] = (n3 < 6) ? 0.5f * b3g[n3] : 0.0f;
    }

    const int rowb = blockIdx.x * 256 + w * 64;   // this wave's 64 rows

    // ---- prefetch all four passes' inputs (q==0 lanes) ----
    half8 bIn[4] = {{}, {}, {}, {}};
    if (q == 0) {
        #pragma unroll
        for (int p = 0; p < 4; ++p) {
            int m = rowb + p * 16 + ln;
            bIn[p][0] = (_Float16)tg[m];
            bIn[p][1] = (_Float16)blg[3 * m + 0];
            bIn[p][2] = (_Float16)blg[3 * m + 1];
            bIn[p][3] = (_Float16)blg[3 * m + 2];
        }
    }

    __syncthreads();

    // ---- 2 groups x 2 passes of 16 rows; circuit + store per group ----
    #pragma unroll 1
    for (int g = 0; g < 2; ++g) {
        #pragma unroll
        for (int p = 0; p < 2; ++p) {
            const int gp = g * 2 + p;
            // layer 1 (x' domain): ungated padded A; C-init = b1' frag
            f32x4 acc1[8];
            #pragma unroll
            for (int nt = 0; nt < 8; ++nt) {
                half8 a1 = *(const half8*)&sW1[nt * 128 + ln * 8];
                f32x4 bb = *(const f32x4*)&sB1[nt * 16 + 4 * q];
                acc1[nt] = __builtin_amdgcn_mfma_f32_16x16x32_f16(a1, bIn[gp], bb, 0, 0, 0);
            }

            // epilogue 1: exp2-silu -> layer-2 B frags (scaled domain)
            half8 bf2[4];
            #pragma unroll
            for (int s = 0; s < 4; ++s) {
                Half8U u;
                #pragma unroll
                for (int hj = 0; hj < 2; ++hj) {
                    int nt = 2 * s + hj;
                    u.h2[hj * 2 + 0] = silu2x(acc1[nt][0], acc1[nt][1]);
                    u.h2[hj * 2 + 1] = silu2x(acc1[nt][2], acc1[nt][3]);
                }
                bf2[s] = u.v;
            }

            // layer 2: fragment-major A (unscaled W2); C-init = b2' at s==0
            f32x4 acc2[8];
            #pragma unroll
            for (int s = 0; s < 4; ++s) {
                #pragma unroll
                for (int nt = 0; nt < 8; ++nt) {
                    half8 a2 = *(const half8*)&sW2[(s * 8 + nt) * 512 + lane * 8];
                    if (s == 0) {
                        f32x4 bb = *(const f32x4*)&sB2[nt * 16 + 4 * q];
                        acc2[nt] = __builtin_amdgcn_mfma_f32_16x16x32_f16(a2, bf2[0], bb, 0, 0, 0);
                    } else {
                        acc2[nt] = __builtin_amdgcn_mfma_f32_16x16x32_f16(a2, bf2[s], acc2[nt], 0, 0, 0);
                    }
                }
            }

            // epilogue 2: exp2-silu -> layer-3 B frags
            half8 bf3[4];
            #pragma unroll
            for (int s = 0; s < 4; ++s) {
                Half8U u;
                #pragma unroll
                for (int hj = 0; hj < 2; ++hj) {
                    int nt = 2 * s + hj;
                    u.h2[hj * 2 + 0] = silu2x(acc2[nt][0], acc2[nt][1]);
                    u.h2[hj * 2 + 1] = silu2x(acc2[nt][2], acc2[nt][3]);
                }
                bf3[s] = u.v;
            }

            // layer 3: ungated padded A (x 0.5/c); C-init = b3/2 regs
            f32x4 acc3 = (f32x4){b3c[0], b3c[1], b3c[2], b3c[3]};
            #pragma unroll
            for (int s = 0; s < 4; ++s) {
                half8 a3 = *(const half8*)&sW3[s * 512 + ln * 32 + q * 8];
                acc3 = __builtin_amdgcn_mfma_f32_16x16x32_f16(a3, bf3[s], acc3, 0, 0, 0);
            }

            // epilogue 3: pack half-angle params fp16 -> wave strip
            int row = p * 16 + ln;
            if (q == 0) {
                sPU[row * 3 + 0] = pk16(acc3[0], acc3[1]);  // th1/2, ph1/2
                sPU[row * 3 + 1] = pk16(acc3[2], acc3[3]);  // th2/2, ph2/2
            } else if (q == 1) {
                sPU[row * 3 + 2] = pk16(acc3[0], acc3[1]);  // th3/2, ph3/2
            }
        }
        DSFENCE();   // params visible to all lanes

        // ---- circuit sim: lanes 0..31, one row each (half-angle params) ----
        if (lane < 32) {
            half2 h0 = __builtin_bit_cast(half2, sPU[lane * 3 + 0]);
            half2 h1 = __builtin_bit_cast(half2, sPU[lane * 3 + 1]);
            half2 h2 = __builtin_bit_cast(half2, sPU[lane * 3 + 2]);
            float pr[6] = {(float)h0[0], (float)h0[1], (float)h1[0],
                           (float)h1[1], (float)h2[0], (float)h2[1]};
            float ar = 1.f, ai = 0.f, br = 0.f, bi = 0.f;
            #pragma unroll
            for (int l = 0; l < 3; ++l) {
                float th = pr[2 * l];
                float ph = pr[2 * l + 1];
                float s1, c1, se, ce;
                __sincosf(th, &s1, &c1);
                float a1r = c1 * ar - s1 * br, a1i = c1 * ai - s1 * bi;
                float b1r = s1 * ar + c1 * br, b1i = s1 * ai + c1 * bi;
                __sincosf(ph, &se, &ce);
                ar = ce * a1r + se * a1i; ai = ce * a1i - se * a1r;
                br = ce * b1r - se * b1i; bi = ce * b1i + se * b1r;
            }
            // same-lane same-address: ordered within a lane
            sPF[lane * 3 + 0] = 2.f * (ar * br + ai * bi);
            sPF[lane * 3 + 1] = 2.f * (ar * bi - ai * br);
            sPF[lane * 3 + 2] = ar * ar + ai * ai - br * br - bi * bi;
        }
        DSFENCE();   // results visible cross-lane

        // ---- coalesced stores: 96 floats per group, 48-lane dwordx2 ----
        if (lane < 48) {
            f32x2 vv = *(const f32x2*)&sPF[2 * lane];
            *(f32x2*)&out[3 * (rowb + g * 32) + 2 * lane] = vv;
        }
        DSFENCE();   // strip reads complete before next group's param writes
    }
}

extern "C" void kernel_launch(void* const* d_in, const int* in_sizes, int n_in,
                              void* d_out, int out_size, void* d_ws, size_t ws_size,
                              hipStream_t stream) {
    const float* t  = (const float*)d_in[0];
    const float* bl = (const float*)d_in[1];
    const float* W1 = (const float*)d_in[2];
    const float* b1 = (const float*)d_in[3];
    const float* W2 = (const float*)d_in[4];
    const float* b2 = (const float*)d_in[5];
    const float* W3 = (const float*)d_in[6];
    const float* b3 = (const float*)d_in[7];
    float* out = (float*)d_out;

    if (ws_size >= WS_IMG_BYTES) {
        unsigned char* ws = (unsigned char*)d_ws;
        qvf_pack<<<65, 256, 0, stream>>>(W1, b1, W2, b2, W3, b3, ws);
        qvf_kernel<true><<<NBLOCKS, 256, 0, stream>>>(t, bl, W1, b1, W2, b2, W3, b3, ws, out);
    } else {
        qvf_kernel<false><<<NBLOCKS, 256, 0, stream>>>(t, bl, W1, b1, W2, b2, W3, b3, nullptr, out);
    }
}